// Round 5
// baseline (39.297 us; speedup 1.0000x reference)
//
#include <hip/hip_runtime.h>

// Problem constants (match reference)
#define NS (1 << 20)          // samples per segment
#define THREADS 256
#define TABN 4096             // interp cells per segment (nodes 0..TABN)
#define TABSTRIDE 4160        // floats per segment table slot (65*64, float4-aligned)

// build kernel: 64 nodes per block, 4-way j-split per node
#define BNODES 64
#define BBPS 65               // ceil((TABN+1)/BNODES)
#define BGRID (4 * BBPS)      // 260

// eval kernel geometry
#define MILP 16
#define MSPB (THREADS * MILP)             // 4096 samples per block
#define MBPS (NS / MSPB)                  // 256 blocks per seg
#define MGRID (4 * MBPS)                  // 1024

// fallback (direct) kernel geometry
#define FILP 8
#define FSPB (THREADS * FILP)
#define FBPS (NS / FSPB)                  // 512
#define FGRID (4 * FBPS)                  // 2048

#define SCALE 262144.0        // 2^18 fixed-point scale for deterministic i64 reduce
#define WS_NEED ((size_t)(256 + 4 * TABSTRIDE * sizeof(float)))

typedef float v2f __attribute__((ext_vector_type(2)));

// Per-segment parameterization (validated on HW rounds 1/3/4, absmax 0.0):
// seg 0: u_y1  (jump_y, +1): val = 3*dphi1 - 5*corr
// seg 1: u_ym1 (jump_y, -1): val = 1*dphi1 - 5*corr
// seg 2: u_x1  (jump_x, +1): val = 1*dphi1 - 3*corr
// seg 3: u_xm1 (jump_x, -1): val = -1*dphi1 - 7*corr

// ---------------- table build: G_seg at nodes i/TABN, i in [0, TABN] ----------------
__global__ __launch_bounds__(THREADS) void build_tab(
    const float* __restrict__ sW1, const float* __restrict__ sb1,
    const float* __restrict__ sW2, const float* __restrict__ sb2,
    const float* __restrict__ jW1, const float* __restrict__ jb1,
    const float* __restrict__ jW2, const float* __restrict__ jb2,
    float* __restrict__ tab, unsigned long long* __restrict__ ctrs)
{
    __shared__ __align__(16) float s_w[64][12];
    __shared__ float s_swv[2];

    const int bid = blockIdx.x;
    const int seg = bid / BBPS;
    const int blk = bid - seg * BBPS;
    const int tid = threadIdx.x;

    if (bid == 0 && tid == 0) { ctrs[0] = 0ull; ctrs[1] = 0ull; }  // zero reduce counters for eval

    const int ca  = (seg < 2) ? 0 : 1;
    const int pp  = 1 - ca;
    const int kv  = (seg < 2) ? 2 : 1;
    const int kd2 = 3 - kv;
    const float sign  = (seg & 1) ? -1.0f : 1.0f;
    const float alpha = (seg == 0) ? 3.0f : ((seg == 3) ? -1.0f : 1.0f);
    const float beta  = (seg <  2) ? -5.0f : ((seg == 2) ? -3.0f : -7.0f);
    const float TL = 2.885390081777927f;             // 2*log2(e)

    if (tid < 64) {
        const int j = tid;
        float sw1c = sW1[ca * 64 + j], jw1c = jW1[ca * 64 + j];
        float sw1p = sW1[pp * 64 + j], jw1p = jW1[pp * 64 + j];
        s_w[j][0] = sw1c * TL * sign;                // pre = wc*u + bb (sign folded)
        s_w[j][1] = jw1c * TL * sign;
        s_w[j][2] = sb1[j] * TL;
        s_w[j][3] = jb1[j] * TL;
        s_w[j][4] = 4.0f * sw1p * sW2[j * 3 + 0];    // x4: tp = t/4
        s_w[j][5] = 4.0f * jw1p * jW2[j * 3 + 0];
        s_w[j][6] = 4.0f * sw1p * sW2[j * 3 + kd2];
        s_w[j][7] = 4.0f * jw1p * jW2[j * 3 + kd2];
        s_w[j][8] = sW2[j * 3 + kv];
        s_w[j][9] = jW2[j * 3 + kv];
    }
    __syncthreads();
    if (tid < 2) {
        float s = 0.0f;
        for (int j = 0; j < 64; ++j) s += s_w[j][8 + tid];
        s_swv[tid] = s + (tid ? jb2[kv] : sb2[kv]);  // V = swv - 2*sum(g*wv)
    }
    __syncthreads();

    // 4 threads per node: part p handles j in [16p, 16p+16)
    const int part = tid & 3;
    const int node = blk * BNODES + (tid >> 2);
    const float u = (float)node * (1.0f / TABN);

    float Vgs = 0.0f, D0s = 0.0f, D2s = 0.0f, Vgj = 0.0f, D0j = 0.0f, D2j = 0.0f;
    #pragma unroll 4
    for (int jj = 0; jj < 16; ++jj) {
        const int j = (part << 4) | jj;
        const float4 A = *(const float4*)&s_w[j][0];
        const float4 B = *(const float4*)&s_w[j][4];
        const v2f   wv = *(const v2f*)&s_w[j][8];
        float ps = fmaf(A.x, u, A.z);
        float Es = __builtin_amdgcn_exp2f(ps);
        float gs = __builtin_amdgcn_rcpf(Es + 1.0f);
        float ts = fmaf(-gs, gs, gs);
        Vgs = fmaf(gs, wv.x, Vgs);
        D0s = fmaf(ts, B.x, D0s);
        D2s = fmaf(ts, B.z, D2s);
        float pj = fmaf(A.y, u, A.w);
        float Ej = __builtin_amdgcn_exp2f(pj);
        float gj = __builtin_amdgcn_rcpf(Ej + 1.0f);
        float tj = fmaf(-gj, gj, gj);
        Vgj = fmaf(gj, wv.y, Vgj);
        D0j = fmaf(tj, B.y, D0j);
        D2j = fmaf(tj, B.w, D2j);
    }
    // combine the 4 j-parts (lanes 4k..4k+3 hold the same node)
    #pragma unroll
    for (int m = 1; m <= 2; m <<= 1) {
        Vgs += __shfl_xor(Vgs, m); D0s += __shfl_xor(D0s, m); D2s += __shfl_xor(D2s, m);
        Vgj += __shfl_xor(Vgj, m); D0j += __shfl_xor(D0j, m); D2j += __shfl_xor(D2j, m);
    }

    float r = __builtin_amdgcn_sqrtf(fmaf(u, u, 1e-12f));
    float inv_r = __builtin_amdgcn_rcpf(r);
    float rcb = fmaxf(fmaf(-2.0f, r, 1.0f), 0.0f);   // max(1 - r/0.5, 0)
    float rc = rcb * rcb;
    float rl = __builtin_amdgcn_exp2f(0.66666666666666663f * __builtin_amdgcn_logf(r));
    float rcrl = rc * rl;                            // rc * r^(2/3)
    float rcrlm1 = rcrl * inv_r;                     // rc * r^(2/3 - 1)
    float q = u * inv_r;
    float bcv = fmaf(-u, u, 1.0f);
    float wgt = fminf(40.0f * u, 1.0f);
    float VS = fmaf(-2.0f, Vgs, s_swv[0]);
    float VJ = fmaf(-2.0f, Vgj, s_swv[1]);
    float dphi1 = fmaf(D2s, q, D0s) * rcrl + bcv * fmaf(D2j, u, D0j);
    float corr = VJ * bcv + VS * rcrlm1;
    float val = fmaf(alpha, dphi1, beta * corr);
    float G = val * val * wgt;

    if (part == 0 && node <= TABN) tab[seg * TABSTRIDE + node] = G;
}

// ---------------- main: LDS-staged G table, linear interp, i64 atomic reduce ----------------
__global__ __launch_bounds__(THREADS) void eval_main(
    const float* __restrict__ u0p, const float* __restrict__ u1p,
    const float* __restrict__ u2p, const float* __restrict__ u3p,
    const float* __restrict__ tab, unsigned long long* __restrict__ ctrs,
    float* __restrict__ out)
{
    __shared__ __align__(16) float s_tab[TABN + 4];   // 16.4 KiB
    __shared__ float s_red[THREADS / 64];

    const int bid = blockIdx.x;
    const int seg = bid >> 8;                      // MBPS = 256
    const int chunk = bid & 255;
    const int tid = threadIdx.x;

    // stage this segment's table (4096 floats as float4 + node 4096)
    {
        const float4* src = (const float4*)(tab + seg * TABSTRIDE);
        float4* dst = (float4*)s_tab;
        #pragma unroll
        for (int t = 0; t < 4; ++t)
            dst[t * THREADS + tid] = src[t * THREADS + tid];
        if (tid == 0) s_tab[TABN] = tab[seg * TABSTRIDE + TABN];
    }
    __syncthreads();

    const float* up = (seg == 0) ? u0p : (seg == 1) ? u1p : (seg == 2) ? u2p : u3p;
    const float4* up4 = (const float4*)up;

    float acc = 0.0f;
    #pragma unroll
    for (int t = 0; t < MILP / 4; ++t) {
        float4 u4 = up4[chunk * (MSPB / 4) + t * THREADS + tid];
        float us[4] = {u4.x, u4.y, u4.z, u4.w};
        #pragma unroll
        for (int s = 0; s < 4; ++s) {
            float fidx = us[s] * (float)TABN;
            int i = (int)fidx;
            i = (i < TABN - 1) ? i : (TABN - 1);
            float f = fidx - (float)i;
            float T0 = s_tab[i];
            float T1 = s_tab[i + 1];
            acc += fmaf(f, T1 - T0, T0);
        }
    }

    #pragma unroll
    for (int off = 32; off; off >>= 1) acc += __shfl_down(acc, off);
    const int lane = tid & 63, wid = tid >> 6;
    if (lane == 0) s_red[wid] = acc;
    __syncthreads();
    if (tid == 0) {
        float bs = s_red[0] + s_red[1] + s_red[2] + s_red[3];
        // deterministic reduce: fixed-point i64 atomics (integer adds commute exactly)
        unsigned long long iv = (unsigned long long)(long long)((double)bs * SCALE);
        atomicAdd(&ctrs[0], iv);
        __threadfence();
        unsigned long long prev = atomicAdd(&ctrs[1], 1ull);
        if (prev == (unsigned long long)(MGRID - 1)) {
            unsigned long long tot = atomicAdd(&ctrs[0], 0ull);  // device-scope coherent read
            out[0] = (float)((double)(long long)tot * (1.0 / (SCALE * (double)NS)));
        }
    }
}

// ---------------- fallback: direct evaluation (R3, validated) ----------------
__global__ __launch_bounds__(THREADS, 4) void direct_stage1(
    const float* __restrict__ u0p, const float* __restrict__ u1p,
    const float* __restrict__ u2p, const float* __restrict__ u3p,
    const float* __restrict__ sW1, const float* __restrict__ sb1,
    const float* __restrict__ sW2, const float* __restrict__ sb2,
    const float* __restrict__ jW1, const float* __restrict__ jb1,
    const float* __restrict__ jW2, const float* __restrict__ jb2,
    float* __restrict__ out)
{
    __shared__ __align__(16) float s_w[64][12];
    __shared__ float s_swv[2];
    __shared__ float s_red[THREADS / 64];

    const int bid = blockIdx.x;
    const int seg = bid / FBPS;
    const int chunk = bid - seg * FBPS;
    const int tid = threadIdx.x;

    const int ca  = (seg < 2) ? 0 : 1;
    const int pp  = 1 - ca;
    const int kv  = (seg < 2) ? 2 : 1;
    const int kd2 = 3 - kv;
    const float sign  = (seg & 1) ? -1.0f : 1.0f;
    const float alpha = (seg == 0) ? 3.0f : ((seg == 3) ? -1.0f : 1.0f);
    const float beta  = (seg <  2) ? -5.0f : ((seg == 2) ? -3.0f : -7.0f);
    const float TL = 2.885390081777927f;

    if (tid < 64) {
        const int j = tid;
        float sw1c = sW1[ca * 64 + j], jw1c = jW1[ca * 64 + j];
        float sw1p = sW1[pp * 64 + j], jw1p = jW1[pp * 64 + j];
        s_w[j][0] = sw1c * TL * sign;
        s_w[j][1] = jw1c * TL * sign;
        s_w[j][2] = sb1[j] * TL;
        s_w[j][3] = jb1[j] * TL;
        s_w[j][4] = 4.0f * sw1p * sW2[j * 3 + 0];
        s_w[j][5] = 4.0f * jw1p * jW2[j * 3 + 0];
        s_w[j][6] = 4.0f * sw1p * sW2[j * 3 + kd2];
        s_w[j][7] = 4.0f * jw1p * jW2[j * 3 + kd2];
        s_w[j][8] = sW2[j * 3 + kv];
        s_w[j][9] = jW2[j * 3 + kv];
    }
    __syncthreads();
    if (tid < 2) {
        float s = 0.0f;
        for (int j = 0; j < 64; ++j) s += s_w[j][8 + tid];
        s_swv[tid] = s + (tid ? jb2[kv] : sb2[kv]);
    }
    __syncthreads();

    const float* up = (seg == 0) ? u0p : (seg == 1) ? u1p : (seg == 2) ? u2p : u3p;
    const float4* up4 = (const float4*)up;
    const int base = chunk * (FSPB / 4) + tid;
    const float4 a4 = up4[base];
    const float4 b4 = up4[base + THREADS];
    const float uu[FILP] = {a4.x, a4.y, a4.z, a4.w, b4.x, b4.y, b4.z, b4.w};

    float Vgs[FILP], D0s[FILP], D2s[FILP], Vgj[FILP], D0j[FILP], D2j[FILP];
    #pragma unroll
    for (int s = 0; s < FILP; ++s) {
        Vgs[s] = 0.0f; D0s[s] = 0.0f; D2s[s] = 0.0f;
        Vgj[s] = 0.0f; D0j[s] = 0.0f; D2j[s] = 0.0f;
    }

    #pragma unroll 2
    for (int j = 0; j < 64; ++j) {
        const float4 A = *(const float4*)&s_w[j][0];
        const float4 B = *(const float4*)&s_w[j][4];
        const v2f   wv = *(const v2f*)&s_w[j][8];
        #pragma unroll
        for (int s = 0; s < FILP; ++s) {
            float ps = fmaf(A.x, uu[s], A.z);
            float Es = __builtin_amdgcn_exp2f(ps);
            float gs = __builtin_amdgcn_rcpf(Es + 1.0f);
            float ts = fmaf(-gs, gs, gs);
            Vgs[s] = fmaf(gs, wv.x, Vgs[s]);
            D0s[s] = fmaf(ts, B.x, D0s[s]);
            D2s[s] = fmaf(ts, B.z, D2s[s]);
            float pj = fmaf(A.y, uu[s], A.w);
            float Ej = __builtin_amdgcn_exp2f(pj);
            float gj = __builtin_amdgcn_rcpf(Ej + 1.0f);
            float tj = fmaf(-gj, gj, gj);
            Vgj[s] = fmaf(gj, wv.y, Vgj[s]);
            D0j[s] = fmaf(tj, B.y, D0j[s]);
            D2j[s] = fmaf(tj, B.w, D2j[s]);
        }
    }

    const float swv_s = s_swv[0], swv_j = s_swv[1];
    float acc = 0.0f;
    #pragma unroll
    for (int s = 0; s < FILP; ++s) {
        const float u = uu[s];
        float r = __builtin_amdgcn_sqrtf(fmaf(u, u, 1e-12f));
        float inv_r = __builtin_amdgcn_rcpf(r);
        float rcb = fmaxf(fmaf(-2.0f, r, 1.0f), 0.0f);
        float rc = rcb * rcb;
        float rl = __builtin_amdgcn_exp2f(0.66666666666666663f * __builtin_amdgcn_logf(r));
        float rcrl = rc * rl;
        float rcrlm1 = rcrl * inv_r;
        float q = u * inv_r;
        float bcv = fmaf(-u, u, 1.0f);
        float wgt = fminf(40.0f * u, 1.0f);
        float VS = fmaf(-2.0f, Vgs[s], swv_s);
        float VJ = fmaf(-2.0f, Vgj[s], swv_j);
        float dphi1 = fmaf(D2s[s], q, D0s[s]) * rcrl
                    + bcv * fmaf(D2j[s], u, D0j[s]);
        float corr = VJ * bcv + VS * rcrlm1;
        float val = fmaf(alpha, dphi1, beta * corr);
        acc = fmaf(val * val, wgt, acc);
    }

    #pragma unroll
    for (int off = 32; off; off >>= 1) acc += __shfl_down(acc, off);
    const int lane = tid & 63, wid = tid >> 6;
    if (lane == 0) s_red[wid] = acc;
    __syncthreads();
    if (tid == 0) {
        float bs = s_red[0] + s_red[1] + s_red[2] + s_red[3];
        atomicAdd(out, bs * (1.0f / (float)NS));
    }
}

extern "C" void kernel_launch(void* const* d_in, const int* in_sizes, int n_in,
                              void* d_out, int out_size, void* d_ws, size_t ws_size,
                              hipStream_t stream) {
    const float* u_y1  = (const float*)d_in[0];
    const float* u_ym1 = (const float*)d_in[1];
    const float* u_x1  = (const float*)d_in[2];
    const float* u_xm1 = (const float*)d_in[3];
    const float* sW1 = (const float*)d_in[4];
    const float* sb1 = (const float*)d_in[5];
    const float* sW2 = (const float*)d_in[6];
    const float* sb2 = (const float*)d_in[7];
    const float* jW1 = (const float*)d_in[8];
    const float* jb1 = (const float*)d_in[9];
    const float* jW2 = (const float*)d_in[10];
    const float* jb2 = (const float*)d_in[11];
    float* out = (float*)d_out;

    if (ws_size >= WS_NEED) {
        unsigned long long* ctrs = (unsigned long long*)d_ws;   // [0]=sum, [1]=count
        float* tab = (float*)((char*)d_ws + 256);               // 4 * TABSTRIDE floats
        build_tab<<<BGRID, THREADS, 0, stream>>>(
            sW1, sb1, sW2, sb2, jW1, jb1, jW2, jb2, tab, ctrs);
        eval_main<<<MGRID, THREADS, 0, stream>>>(
            u_y1, u_ym1, u_x1, u_xm1, tab, ctrs, out);
    } else {
        hipMemsetAsync(d_out, 0, sizeof(float), stream);
        direct_stage1<<<FGRID, THREADS, 0, stream>>>(
            u_y1, u_ym1, u_x1, u_xm1, sW1, sb1, sW2, sb2, jW1, jb1, jW2, jb2,
            out);
    }
}

// Round 6
// 26.824 us; speedup vs baseline: 1.4650x; 1.4650x over previous
//
#include <hip/hip_runtime.h>

// Problem constants (match reference)
#define NS (1 << 20)          // samples per segment
#define THREADS 256
#define TABN 4096             // interp cells per segment (nodes 0..TABN)
#define TABSTRIDE 4160        // floats per segment table slot (float4-aligned)

// build kernel: 64 nodes per block, 4-way j-split per node
#define BNODES 64
#define BBPS 65               // ceil((TABN+1)/BNODES)
#define BGRID (4 * BBPS)      // 260

// eval kernel geometry
#define MILP 16
#define MSPB (THREADS * MILP)             // 4096 samples per block
#define MBPS (NS / MSPB)                  // 256 blocks per seg
#define MGRID (4 * MBPS)                  // 1024

// fallback (direct) kernel geometry
#define FILP 8
#define FSPB (THREADS * FILP)
#define FBPS (NS / FSPB)                  // 512
#define FGRID (4 * FBPS)                  // 2048

#define SCALE 262144.0        // 2^18 fixed-point scale for deterministic i64 reduce
#define CNT_BITS 12           // low 12 bits of the packed atomic = arrival count
#define WS_NEED ((size_t)(256 + 4 * TABSTRIDE * sizeof(float)))

typedef float v2f __attribute__((ext_vector_type(2)));

// Per-segment parameterization (validated on HW rounds 1/3/4/5, absmax 0.0):
// seg 0: u_y1  (jump_y, +1): val = 3*dphi1 - 5*corr
// seg 1: u_ym1 (jump_y, -1): val = 1*dphi1 - 5*corr
// seg 2: u_x1  (jump_x, +1): val = 1*dphi1 - 3*corr
// seg 3: u_xm1 (jump_x, -1): val = -1*dphi1 - 7*corr

// ---------------- table build: G_seg at nodes i/TABN, i in [0, TABN] ----------------
__global__ __launch_bounds__(THREADS) void build_tab(
    const float* __restrict__ sW1, const float* __restrict__ sb1,
    const float* __restrict__ sW2, const float* __restrict__ sb2,
    const float* __restrict__ jW1, const float* __restrict__ jb1,
    const float* __restrict__ jW2, const float* __restrict__ jb2,
    float* __restrict__ tab, unsigned long long* __restrict__ ctrs)
{
    __shared__ __align__(16) float s_w[64][12];
    __shared__ float s_swv[2];

    const int bid = blockIdx.x;
    const int seg = bid / BBPS;
    const int blk = bid - seg * BBPS;
    const int tid = threadIdx.x;

    if (bid == 0 && tid == 0) ctrs[0] = 0ull;   // zero packed reduce counter for eval

    const int ca  = (seg < 2) ? 0 : 1;
    const int pp  = 1 - ca;
    const int kv  = (seg < 2) ? 2 : 1;
    const int kd2 = 3 - kv;
    const float sign  = (seg & 1) ? -1.0f : 1.0f;
    const float alpha = (seg == 0) ? 3.0f : ((seg == 3) ? -1.0f : 1.0f);
    const float beta  = (seg <  2) ? -5.0f : ((seg == 2) ? -3.0f : -7.0f);
    const float TL = 2.885390081777927f;             // 2*log2(e)

    if (tid < 64) {
        const int j = tid;
        float sw1c = sW1[ca * 64 + j], jw1c = jW1[ca * 64 + j];
        float sw1p = sW1[pp * 64 + j], jw1p = jW1[pp * 64 + j];
        s_w[j][0] = sw1c * TL * sign;                // pre = wc*u + bb (sign folded)
        s_w[j][1] = jw1c * TL * sign;
        s_w[j][2] = sb1[j] * TL;
        s_w[j][3] = jb1[j] * TL;
        s_w[j][4] = 4.0f * sw1p * sW2[j * 3 + 0];    // x4: tp = t/4
        s_w[j][5] = 4.0f * jw1p * jW2[j * 3 + 0];
        s_w[j][6] = 4.0f * sw1p * sW2[j * 3 + kd2];
        s_w[j][7] = 4.0f * jw1p * jW2[j * 3 + kd2];
        s_w[j][8] = sW2[j * 3 + kv];
        s_w[j][9] = jW2[j * 3 + kv];
    }
    __syncthreads();
    if (tid < 2) {
        float s = 0.0f;
        for (int j = 0; j < 64; ++j) s += s_w[j][8 + tid];
        s_swv[tid] = s + (tid ? jb2[kv] : sb2[kv]);  // V = swv - 2*sum(g*wv)
    }
    __syncthreads();

    // 4 threads per node: part p handles j in [16p, 16p+16)
    const int part = tid & 3;
    const int node = blk * BNODES + (tid >> 2);
    const float u = (float)node * (1.0f / TABN);

    float Vgs = 0.0f, D0s = 0.0f, D2s = 0.0f, Vgj = 0.0f, D0j = 0.0f, D2j = 0.0f;
    #pragma unroll 4
    for (int jj = 0; jj < 16; ++jj) {
        const int j = (part << 4) | jj;
        const float4 A = *(const float4*)&s_w[j][0];
        const float4 B = *(const float4*)&s_w[j][4];
        const v2f   wv = *(const v2f*)&s_w[j][8];
        float ps = fmaf(A.x, u, A.z);
        float Es = __builtin_amdgcn_exp2f(ps);
        float gs = __builtin_amdgcn_rcpf(Es + 1.0f);
        float ts = fmaf(-gs, gs, gs);
        Vgs = fmaf(gs, wv.x, Vgs);
        D0s = fmaf(ts, B.x, D0s);
        D2s = fmaf(ts, B.z, D2s);
        float pj = fmaf(A.y, u, A.w);
        float Ej = __builtin_amdgcn_exp2f(pj);
        float gj = __builtin_amdgcn_rcpf(Ej + 1.0f);
        float tj = fmaf(-gj, gj, gj);
        Vgj = fmaf(gj, wv.y, Vgj);
        D0j = fmaf(tj, B.y, D0j);
        D2j = fmaf(tj, B.w, D2j);
    }
    // combine the 4 j-parts (lanes 4k..4k+3 hold the same node)
    #pragma unroll
    for (int m = 1; m <= 2; m <<= 1) {
        Vgs += __shfl_xor(Vgs, m); D0s += __shfl_xor(D0s, m); D2s += __shfl_xor(D2s, m);
        Vgj += __shfl_xor(Vgj, m); D0j += __shfl_xor(D0j, m); D2j += __shfl_xor(D2j, m);
    }

    float r = __builtin_amdgcn_sqrtf(fmaf(u, u, 1e-12f));
    float inv_r = __builtin_amdgcn_rcpf(r);
    float rcb = fmaxf(fmaf(-2.0f, r, 1.0f), 0.0f);   // max(1 - r/0.5, 0)
    float rc = rcb * rcb;
    float rl = __builtin_amdgcn_exp2f(0.66666666666666663f * __builtin_amdgcn_logf(r));
    float rcrl = rc * rl;                            // rc * r^(2/3)
    float rcrlm1 = rcrl * inv_r;                     // rc * r^(2/3 - 1)
    float q = u * inv_r;
    float bcv = fmaf(-u, u, 1.0f);
    float wgt = fminf(40.0f * u, 1.0f);
    float VS = fmaf(-2.0f, Vgs, s_swv[0]);
    float VJ = fmaf(-2.0f, Vgj, s_swv[1]);
    float dphi1 = fmaf(D2s, q, D0s) * rcrl + bcv * fmaf(D2j, u, D0j);
    float corr = VJ * bcv + VS * rcrlm1;
    float val = fmaf(alpha, dphi1, beta * corr);
    float G = val * val * wgt;                       // >= 0 always

    if (part == 0 && node <= TABN) tab[seg * TABSTRIDE + node] = G;
}

// ---------------- main: LDS-staged G table, linear interp, packed-u64 reduce ----------------
__global__ __launch_bounds__(THREADS) void eval_main(
    const float* __restrict__ u0p, const float* __restrict__ u1p,
    const float* __restrict__ u2p, const float* __restrict__ u3p,
    const float* __restrict__ tab, unsigned long long* __restrict__ ctrs,
    float* __restrict__ out)
{
    __shared__ __align__(16) float s_tab[TABN + 4];   // 16.4 KiB
    __shared__ float s_red[THREADS / 64];

    const int bid = blockIdx.x;
    const int seg = bid >> 8;                      // MBPS = 256
    const int chunk = bid & 255;
    const int tid = threadIdx.x;

    // stage this segment's table (4096 floats as float4 + node 4096)
    {
        const float4* src = (const float4*)(tab + seg * TABSTRIDE);
        float4* dst = (float4*)s_tab;
        #pragma unroll
        for (int t = 0; t < 4; ++t)
            dst[t * THREADS + tid] = src[t * THREADS + tid];
        if (tid == 0) s_tab[TABN] = tab[seg * TABSTRIDE + TABN];
    }
    __syncthreads();

    const float* up = (seg == 0) ? u0p : (seg == 1) ? u1p : (seg == 2) ? u2p : u3p;
    const float4* up4 = (const float4*)up;

    float acc = 0.0f;
    #pragma unroll
    for (int t = 0; t < MILP / 4; ++t) {
        float4 u4 = up4[chunk * (MSPB / 4) + t * THREADS + tid];
        float us[4] = {u4.x, u4.y, u4.z, u4.w};
        #pragma unroll
        for (int s = 0; s < 4; ++s) {
            float fidx = us[s] * (float)TABN;
            int i = (int)fidx;
            i = (i < TABN - 1) ? i : (TABN - 1);
            float f = fidx - (float)i;
            float T0 = s_tab[i];
            float T1 = s_tab[i + 1];
            acc += fmaf(f, T1 - T0, T0);
        }
    }

    #pragma unroll
    for (int off = 32; off; off >>= 1) acc += __shfl_down(acc, off);
    const int lane = tid & 63, wid = tid >> 6;
    if (lane == 0) s_red[wid] = acc;
    __syncthreads();
    if (tid == 0) {
        float bs = s_red[0] + s_red[1] + s_red[2] + s_red[3];   // >= 0
        // fence-free deterministic reduce: ONE u64 atomic carries
        // [sum_fixedpoint : upper 52 bits][arrival count : low 12 bits].
        // Integer adds commute exactly -> bitwise deterministic.
        unsigned long long iv = (unsigned long long)(long long)((double)bs * SCALE);
        unsigned long long old = atomicAdd(&ctrs[0], (iv << CNT_BITS) | 1ull);
        if ((old & ((1ull << CNT_BITS) - 1ull)) == (unsigned long long)(MGRID - 1)) {
            unsigned long long tot = (old >> CNT_BITS) + iv;    // all 1024 block sums
            out[0] = (float)((double)tot * (1.0 / (SCALE * (double)NS)));
        }
    }
}

// ---------------- fallback: direct evaluation (R3, validated) ----------------
__global__ __launch_bounds__(THREADS, 4) void direct_stage1(
    const float* __restrict__ u0p, const float* __restrict__ u1p,
    const float* __restrict__ u2p, const float* __restrict__ u3p,
    const float* __restrict__ sW1, const float* __restrict__ sb1,
    const float* __restrict__ sW2, const float* __restrict__ sb2,
    const float* __restrict__ jW1, const float* __restrict__ jb1,
    const float* __restrict__ jW2, const float* __restrict__ jb2,
    float* __restrict__ out)
{
    __shared__ __align__(16) float s_w[64][12];
    __shared__ float s_swv[2];
    __shared__ float s_red[THREADS / 64];

    const int bid = blockIdx.x;
    const int seg = bid / FBPS;
    const int chunk = bid - seg * FBPS;
    const int tid = threadIdx.x;

    const int ca  = (seg < 2) ? 0 : 1;
    const int pp  = 1 - ca;
    const int kv  = (seg < 2) ? 2 : 1;
    const int kd2 = 3 - kv;
    const float sign  = (seg & 1) ? -1.0f : 1.0f;
    const float alpha = (seg == 0) ? 3.0f : ((seg == 3) ? -1.0f : 1.0f);
    const float beta  = (seg <  2) ? -5.0f : ((seg == 2) ? -3.0f : -7.0f);
    const float TL = 2.885390081777927f;

    if (tid < 64) {
        const int j = tid;
        float sw1c = sW1[ca * 64 + j], jw1c = jW1[ca * 64 + j];
        float sw1p = sW1[pp * 64 + j], jw1p = jW1[pp * 64 + j];
        s_w[j][0] = sw1c * TL * sign;
        s_w[j][1] = jw1c * TL * sign;
        s_w[j][2] = sb1[j] * TL;
        s_w[j][3] = jb1[j] * TL;
        s_w[j][4] = 4.0f * sw1p * sW2[j * 3 + 0];
        s_w[j][5] = 4.0f * jw1p * jW2[j * 3 + 0];
        s_w[j][6] = 4.0f * sw1p * sW2[j * 3 + kd2];
        s_w[j][7] = 4.0f * jw1p * jW2[j * 3 + kd2];
        s_w[j][8] = sW2[j * 3 + kv];
        s_w[j][9] = jW2[j * 3 + kv];
    }
    __syncthreads();
    if (tid < 2) {
        float s = 0.0f;
        for (int j = 0; j < 64; ++j) s += s_w[j][8 + tid];
        s_swv[tid] = s + (tid ? jb2[kv] : sb2[kv]);
    }
    __syncthreads();

    const float* up = (seg == 0) ? u0p : (seg == 1) ? u1p : (seg == 2) ? u2p : u3p;
    const float4* up4 = (const float4*)up;
    const int base = chunk * (FSPB / 4) + tid;
    const float4 a4 = up4[base];
    const float4 b4 = up4[base + THREADS];
    const float uu[FILP] = {a4.x, a4.y, a4.z, a4.w, b4.x, b4.y, b4.z, b4.w};

    float Vgs[FILP], D0s[FILP], D2s[FILP], Vgj[FILP], D0j[FILP], D2j[FILP];
    #pragma unroll
    for (int s = 0; s < FILP; ++s) {
        Vgs[s] = 0.0f; D0s[s] = 0.0f; D2s[s] = 0.0f;
        Vgj[s] = 0.0f; D0j[s] = 0.0f; D2j[s] = 0.0f;
    }

    #pragma unroll 2
    for (int j = 0; j < 64; ++j) {
        const float4 A = *(const float4*)&s_w[j][0];
        const float4 B = *(const float4*)&s_w[j][4];
        const v2f   wv = *(const v2f*)&s_w[j][8];
        #pragma unroll
        for (int s = 0; s < FILP; ++s) {
            float ps = fmaf(A.x, uu[s], A.z);
            float Es = __builtin_amdgcn_exp2f(ps);
            float gs = __builtin_amdgcn_rcpf(Es + 1.0f);
            float ts = fmaf(-gs, gs, gs);
            Vgs[s] = fmaf(gs, wv.x, Vgs[s]);
            D0s[s] = fmaf(ts, B.x, D0s[s]);
            D2s[s] = fmaf(ts, B.z, D2s[s]);
            float pj = fmaf(A.y, uu[s], A.w);
            float Ej = __builtin_amdgcn_exp2f(pj);
            float gj = __builtin_amdgcn_rcpf(Ej + 1.0f);
            float tj = fmaf(-gj, gj, gj);
            Vgj[s] = fmaf(gj, wv.y, Vgj[s]);
            D0j[s] = fmaf(tj, B.y, D0j[s]);
            D2j[s] = fmaf(tj, B.w, D2j[s]);
        }
    }

    const float swv_s = s_swv[0], swv_j = s_swv[1];
    float acc = 0.0f;
    #pragma unroll
    for (int s = 0; s < FILP; ++s) {
        const float u = uu[s];
        float r = __builtin_amdgcn_sqrtf(fmaf(u, u, 1e-12f));
        float inv_r = __builtin_amdgcn_rcpf(r);
        float rcb = fmaxf(fmaf(-2.0f, r, 1.0f), 0.0f);
        float rc = rcb * rcb;
        float rl = __builtin_amdgcn_exp2f(0.66666666666666663f * __builtin_amdgcn_logf(r));
        float rcrl = rc * rl;
        float rcrlm1 = rcrl * inv_r;
        float q = u * inv_r;
        float bcv = fmaf(-u, u, 1.0f);
        float wgt = fminf(40.0f * u, 1.0f);
        float VS = fmaf(-2.0f, Vgs[s], swv_s);
        float VJ = fmaf(-2.0f, Vgj[s], swv_j);
        float dphi1 = fmaf(D2s[s], q, D0s[s]) * rcrl
                    + bcv * fmaf(D2j[s], u, D0j[s]);
        float corr = VJ * bcv + VS * rcrlm1;
        float val = fmaf(alpha, dphi1, beta * corr);
        acc = fmaf(val * val, wgt, acc);
    }

    #pragma unroll
    for (int off = 32; off; off >>= 1) acc += __shfl_down(acc, off);
    const int lane = tid & 63, wid = tid >> 6;
    if (lane == 0) s_red[wid] = acc;
    __syncthreads();
    if (tid == 0) {
        float bs = s_red[0] + s_red[1] + s_red[2] + s_red[3];
        atomicAdd(out, bs * (1.0f / (float)NS));
    }
}

extern "C" void kernel_launch(void* const* d_in, const int* in_sizes, int n_in,
                              void* d_out, int out_size, void* d_ws, size_t ws_size,
                              hipStream_t stream) {
    const float* u_y1  = (const float*)d_in[0];
    const float* u_ym1 = (const float*)d_in[1];
    const float* u_x1  = (const float*)d_in[2];
    const float* u_xm1 = (const float*)d_in[3];
    const float* sW1 = (const float*)d_in[4];
    const float* sb1 = (const float*)d_in[5];
    const float* sW2 = (const float*)d_in[6];
    const float* sb2 = (const float*)d_in[7];
    const float* jW1 = (const float*)d_in[8];
    const float* jb1 = (const float*)d_in[9];
    const float* jW2 = (const float*)d_in[10];
    const float* jb2 = (const float*)d_in[11];
    float* out = (float*)d_out;

    if (ws_size >= WS_NEED) {
        unsigned long long* ctrs = (unsigned long long*)d_ws;   // [0] = packed sum|count
        float* tab = (float*)((char*)d_ws + 256);               // 4 * TABSTRIDE floats
        build_tab<<<BGRID, THREADS, 0, stream>>>(
            sW1, sb1, sW2, sb2, jW1, jb1, jW2, jb2, tab, ctrs);
        eval_main<<<MGRID, THREADS, 0, stream>>>(
            u_y1, u_ym1, u_x1, u_xm1, tab, ctrs, out);
    } else {
        hipMemsetAsync(d_out, 0, sizeof(float), stream);
        direct_stage1<<<FGRID, THREADS, 0, stream>>>(
            u_y1, u_ym1, u_x1, u_xm1, sW1, sb1, sW2, sb2, jW1, jb1, jW2, jb2,
            out);
    }
}

// Round 7
// 16.341 us; speedup vs baseline: 2.4048x; 1.6415x over previous
//
#include <hip/hip_runtime.h>

// Problem constants (match reference)
#define NS (1 << 20)          // samples per segment
#define THREADS 256
#define TABN 4096             // interp cells per segment (nodes 0..TABN)
#define TABSTRIDE 4160        // floats per segment table slot (float4-aligned)

// build kernel: 64 nodes per block, 4-way j-split per node
#define BNODES 64
#define BBPS 65               // ceil((TABN+1)/BNODES)
#define BGRID (4 * BBPS)      // 260

// eval kernel geometry
#define MILP 32
#define MSPB (THREADS * MILP)             // 8192 samples per block
#define MBPS (NS / MSPB)                  // 128 blocks per seg
#define MGRID (4 * MBPS)                  // 512

// fallback (direct) kernel geometry
#define FILP 8
#define FSPB (THREADS * FILP)
#define FBPS (NS / FSPB)                  // 512
#define FGRID (4 * FBPS)                  // 2048

#define TAB_BYTES ((size_t)(4 * TABSTRIDE * sizeof(float)))
#define WS_NEED (TAB_BYTES + 4096)

typedef float v2f __attribute__((ext_vector_type(2)));

// Per-segment parameterization (validated on HW rounds 1/3/4/5/6, absmax 0.0):
// seg 0: u_y1  (jump_y, +1): val = 3*dphi1 - 5*corr
// seg 1: u_ym1 (jump_y, -1): val = 1*dphi1 - 5*corr
// seg 2: u_x1  (jump_x, +1): val = 1*dphi1 - 3*corr
// seg 3: u_xm1 (jump_x, -1): val = -1*dphi1 - 7*corr

// ---------------- table build: G_seg at nodes i/TABN, i in [0, TABN] ----------------
__global__ __launch_bounds__(THREADS) void build_tab(
    const float* __restrict__ sW1, const float* __restrict__ sb1,
    const float* __restrict__ sW2, const float* __restrict__ sb2,
    const float* __restrict__ jW1, const float* __restrict__ jb1,
    const float* __restrict__ jW2, const float* __restrict__ jb2,
    float* __restrict__ tab)
{
    __shared__ __align__(16) float s_w[64][12];
    __shared__ float s_swv[2];

    const int bid = blockIdx.x;
    const int seg = bid / BBPS;
    const int blk = bid - seg * BBPS;
    const int tid = threadIdx.x;

    const int ca  = (seg < 2) ? 0 : 1;
    const int pp  = 1 - ca;
    const int kv  = (seg < 2) ? 2 : 1;
    const int kd2 = 3 - kv;
    const float sign  = (seg & 1) ? -1.0f : 1.0f;
    const float alpha = (seg == 0) ? 3.0f : ((seg == 3) ? -1.0f : 1.0f);
    const float beta  = (seg <  2) ? -5.0f : ((seg == 2) ? -3.0f : -7.0f);
    const float TL = 2.885390081777927f;             // 2*log2(e)

    if (tid < 64) {
        const int j = tid;
        float sw1c = sW1[ca * 64 + j], jw1c = jW1[ca * 64 + j];
        float sw1p = sW1[pp * 64 + j], jw1p = jW1[pp * 64 + j];
        s_w[j][0] = sw1c * TL * sign;                // pre = wc*u + bb (sign folded)
        s_w[j][1] = jw1c * TL * sign;
        s_w[j][2] = sb1[j] * TL;
        s_w[j][3] = jb1[j] * TL;
        s_w[j][4] = 4.0f * sw1p * sW2[j * 3 + 0];    // x4: tp = t/4
        s_w[j][5] = 4.0f * jw1p * jW2[j * 3 + 0];
        s_w[j][6] = 4.0f * sw1p * sW2[j * 3 + kd2];
        s_w[j][7] = 4.0f * jw1p * jW2[j * 3 + kd2];
        s_w[j][8] = sW2[j * 3 + kv];
        s_w[j][9] = jW2[j * 3 + kv];
    }
    __syncthreads();
    if (tid < 2) {
        float s = 0.0f;
        for (int j = 0; j < 64; ++j) s += s_w[j][8 + tid];
        s_swv[tid] = s + (tid ? jb2[kv] : sb2[kv]);  // V = swv - 2*sum(g*wv)
    }
    __syncthreads();

    // 4 threads per node: part p handles j in [16p, 16p+16)
    const int part = tid & 3;
    const int node = blk * BNODES + (tid >> 2);
    const float u = (float)node * (1.0f / TABN);

    float Vgs = 0.0f, D0s = 0.0f, D2s = 0.0f, Vgj = 0.0f, D0j = 0.0f, D2j = 0.0f;
    #pragma unroll 4
    for (int jj = 0; jj < 16; ++jj) {
        const int j = (part << 4) | jj;
        const float4 A = *(const float4*)&s_w[j][0];
        const float4 B = *(const float4*)&s_w[j][4];
        const v2f   wv = *(const v2f*)&s_w[j][8];
        float ps = fmaf(A.x, u, A.z);
        float Es = __builtin_amdgcn_exp2f(ps);
        float gs = __builtin_amdgcn_rcpf(Es + 1.0f);
        float ts = fmaf(-gs, gs, gs);
        Vgs = fmaf(gs, wv.x, Vgs);
        D0s = fmaf(ts, B.x, D0s);
        D2s = fmaf(ts, B.z, D2s);
        float pj = fmaf(A.y, u, A.w);
        float Ej = __builtin_amdgcn_exp2f(pj);
        float gj = __builtin_amdgcn_rcpf(Ej + 1.0f);
        float tj = fmaf(-gj, gj, gj);
        Vgj = fmaf(gj, wv.y, Vgj);
        D0j = fmaf(tj, B.y, D0j);
        D2j = fmaf(tj, B.w, D2j);
    }
    // combine the 4 j-parts (lanes 4k..4k+3 hold the same node)
    #pragma unroll
    for (int m = 1; m <= 2; m <<= 1) {
        Vgs += __shfl_xor(Vgs, m); D0s += __shfl_xor(D0s, m); D2s += __shfl_xor(D2s, m);
        Vgj += __shfl_xor(Vgj, m); D0j += __shfl_xor(D0j, m); D2j += __shfl_xor(D2j, m);
    }

    float r = __builtin_amdgcn_sqrtf(fmaf(u, u, 1e-12f));
    float inv_r = __builtin_amdgcn_rcpf(r);
    float rcb = fmaxf(fmaf(-2.0f, r, 1.0f), 0.0f);   // max(1 - r/0.5, 0)
    float rc = rcb * rcb;
    float rl = __builtin_amdgcn_exp2f(0.66666666666666663f * __builtin_amdgcn_logf(r));
    float rcrl = rc * rl;                            // rc * r^(2/3)
    float rcrlm1 = rcrl * inv_r;                     // rc * r^(2/3 - 1)
    float q = u * inv_r;
    float bcv = fmaf(-u, u, 1.0f);
    float wgt = fminf(40.0f * u, 1.0f);
    float VS = fmaf(-2.0f, Vgs, s_swv[0]);
    float VJ = fmaf(-2.0f, Vgj, s_swv[1]);
    float dphi1 = fmaf(D2s, q, D0s) * rcrl + bcv * fmaf(D2j, u, D0j);
    float corr = VJ * bcv + VS * rcrlm1;
    float val = fmaf(alpha, dphi1, beta * corr);
    float G = val * val * wgt;

    if (part == 0 && node <= TABN) tab[seg * TABSTRIDE + node] = G;
}

// ---------------- main: LDS-staged G table, linear interp, plain partials ----------------
__global__ __launch_bounds__(THREADS) void eval_main(
    const float* __restrict__ u0p, const float* __restrict__ u1p,
    const float* __restrict__ u2p, const float* __restrict__ u3p,
    const float* __restrict__ tab, float* __restrict__ partials)
{
    __shared__ __align__(16) float s_tab[TABN + 4];   // 16.4 KiB
    __shared__ float s_red[THREADS / 64];

    const int bid = blockIdx.x;
    const int seg = bid >> 7;                      // MBPS = 128
    const int chunk = bid & 127;
    const int tid = threadIdx.x;

    // stage this segment's table (4096 floats as float4 + boundary node 4096)
    {
        const float4* src = (const float4*)(tab + seg * TABSTRIDE);
        float4* dst = (float4*)s_tab;
        #pragma unroll
        for (int t = 0; t < 4; ++t)
            dst[t * THREADS + tid] = src[t * THREADS + tid];
        if (tid == 0) s_tab[TABN] = tab[seg * TABSTRIDE + TABN];
    }
    __syncthreads();

    const float* up = (seg == 0) ? u0p : (seg == 1) ? u1p : (seg == 2) ? u2p : u3p;
    const float4* up4 = (const float4*)up;

    float acc = 0.0f;
    #pragma unroll
    for (int t = 0; t < MILP / 4; ++t) {
        float4 u4 = up4[chunk * (MSPB / 4) + t * THREADS + tid];
        float us[4] = {u4.x, u4.y, u4.z, u4.w};
        #pragma unroll
        for (int s = 0; s < 4; ++s) {
            float fidx = us[s] * (float)TABN;
            int i = (int)fidx;
            i = (i < TABN - 1) ? i : (TABN - 1);
            float f = fidx - (float)i;
            float T0 = s_tab[i];          // pair compiles to ds_read2_b32
            float T1 = s_tab[i + 1];
            acc += fmaf(f, T1 - T0, T0);
        }
    }

    #pragma unroll
    for (int off = 32; off; off >>= 1) acc += __shfl_down(acc, off);
    const int lane = tid & 63, wid = tid >> 6;
    if (lane == 0) s_red[wid] = acc;
    __syncthreads();
    if (tid == 0) partials[bid] = s_red[0] + s_red[1] + s_red[2] + s_red[3];
}

__global__ __launch_bounds__(256) void jump_loss_stage2(
    const float* __restrict__ partials, float* __restrict__ out)
{
    double s = 0.0;
    for (int i = threadIdx.x; i < MGRID; i += 256) s += (double)partials[i];
    #pragma unroll
    for (int off = 32; off; off >>= 1) s += __shfl_down(s, off);
    __shared__ double sr[4];
    int lane = threadIdx.x & 63, wid = threadIdx.x >> 6;
    if (lane == 0) sr[wid] = s;
    __syncthreads();
    if (threadIdx.x == 0) {
        out[0] = (float)((sr[0] + sr[1] + sr[2] + sr[3]) / (double)NS);
    }
}

// ---------------- fallback: direct evaluation (R3, validated) ----------------
__global__ __launch_bounds__(THREADS, 4) void direct_stage1(
    const float* __restrict__ u0p, const float* __restrict__ u1p,
    const float* __restrict__ u2p, const float* __restrict__ u3p,
    const float* __restrict__ sW1, const float* __restrict__ sb1,
    const float* __restrict__ sW2, const float* __restrict__ sb2,
    const float* __restrict__ jW1, const float* __restrict__ jb1,
    const float* __restrict__ jW2, const float* __restrict__ jb2,
    float* __restrict__ out)
{
    __shared__ __align__(16) float s_w[64][12];
    __shared__ float s_swv[2];
    __shared__ float s_red[THREADS / 64];

    const int bid = blockIdx.x;
    const int seg = bid / FBPS;
    const int chunk = bid - seg * FBPS;
    const int tid = threadIdx.x;

    const int ca  = (seg < 2) ? 0 : 1;
    const int pp  = 1 - ca;
    const int kv  = (seg < 2) ? 2 : 1;
    const int kd2 = 3 - kv;
    const float sign  = (seg & 1) ? -1.0f : 1.0f;
    const float alpha = (seg == 0) ? 3.0f : ((seg == 3) ? -1.0f : 1.0f);
    const float beta  = (seg <  2) ? -5.0f : ((seg == 2) ? -3.0f : -7.0f);
    const float TL = 2.885390081777927f;

    if (tid < 64) {
        const int j = tid;
        float sw1c = sW1[ca * 64 + j], jw1c = jW1[ca * 64 + j];
        float sw1p = sW1[pp * 64 + j], jw1p = jW1[pp * 64 + j];
        s_w[j][0] = sw1c * TL * sign;
        s_w[j][1] = jw1c * TL * sign;
        s_w[j][2] = sb1[j] * TL;
        s_w[j][3] = jb1[j] * TL;
        s_w[j][4] = 4.0f * sw1p * sW2[j * 3 + 0];
        s_w[j][5] = 4.0f * jw1p * jW2[j * 3 + 0];
        s_w[j][6] = 4.0f * sw1p * sW2[j * 3 + kd2];
        s_w[j][7] = 4.0f * jw1p * jW2[j * 3 + kd2];
        s_w[j][8] = sW2[j * 3 + kv];
        s_w[j][9] = jW2[j * 3 + kv];
    }
    __syncthreads();
    if (tid < 2) {
        float s = 0.0f;
        for (int j = 0; j < 64; ++j) s += s_w[j][8 + tid];
        s_swv[tid] = s + (tid ? jb2[kv] : sb2[kv]);
    }
    __syncthreads();

    const float* up = (seg == 0) ? u0p : (seg == 1) ? u1p : (seg == 2) ? u2p : u3p;
    const float4* up4 = (const float4*)up;
    const int base = chunk * (FSPB / 4) + tid;
    const float4 a4 = up4[base];
    const float4 b4 = up4[base + THREADS];
    const float uu[FILP] = {a4.x, a4.y, a4.z, a4.w, b4.x, b4.y, b4.z, b4.w};

    float Vgs[FILP], D0s[FILP], D2s[FILP], Vgj[FILP], D0j[FILP], D2j[FILP];
    #pragma unroll
    for (int s = 0; s < FILP; ++s) {
        Vgs[s] = 0.0f; D0s[s] = 0.0f; D2s[s] = 0.0f;
        Vgj[s] = 0.0f; D0j[s] = 0.0f; D2j[s] = 0.0f;
    }

    #pragma unroll 2
    for (int j = 0; j < 64; ++j) {
        const float4 A = *(const float4*)&s_w[j][0];
        const float4 B = *(const float4*)&s_w[j][4];
        const v2f   wv = *(const v2f*)&s_w[j][8];
        #pragma unroll
        for (int s = 0; s < FILP; ++s) {
            float ps = fmaf(A.x, uu[s], A.z);
            float Es = __builtin_amdgcn_exp2f(ps);
            float gs = __builtin_amdgcn_rcpf(Es + 1.0f);
            float ts = fmaf(-gs, gs, gs);
            Vgs[s] = fmaf(gs, wv.x, Vgs[s]);
            D0s[s] = fmaf(ts, B.x, D0s[s]);
            D2s[s] = fmaf(ts, B.z, D2s[s]);
            float pj = fmaf(A.y, uu[s], A.w);
            float Ej = __builtin_amdgcn_exp2f(pj);
            float gj = __builtin_amdgcn_rcpf(Ej + 1.0f);
            float tj = fmaf(-gj, gj, gj);
            Vgj[s] = fmaf(gj, wv.y, Vgj[s]);
            D0j[s] = fmaf(tj, B.y, D0j[s]);
            D2j[s] = fmaf(tj, B.w, D2j[s]);
        }
    }

    const float swv_s = s_swv[0], swv_j = s_swv[1];
    float acc = 0.0f;
    #pragma unroll
    for (int s = 0; s < FILP; ++s) {
        const float u = uu[s];
        float r = __builtin_amdgcn_sqrtf(fmaf(u, u, 1e-12f));
        float inv_r = __builtin_amdgcn_rcpf(r);
        float rcb = fmaxf(fmaf(-2.0f, r, 1.0f), 0.0f);
        float rc = rcb * rcb;
        float rl = __builtin_amdgcn_exp2f(0.66666666666666663f * __builtin_amdgcn_logf(r));
        float rcrl = rc * rl;
        float rcrlm1 = rcrl * inv_r;
        float q = u * inv_r;
        float bcv = fmaf(-u, u, 1.0f);
        float wgt = fminf(40.0f * u, 1.0f);
        float VS = fmaf(-2.0f, Vgs[s], swv_s);
        float VJ = fmaf(-2.0f, Vgj[s], swv_j);
        float dphi1 = fmaf(D2s[s], q, D0s[s]) * rcrl
                    + bcv * fmaf(D2j[s], u, D0j[s]);
        float corr = VJ * bcv + VS * rcrlm1;
        float val = fmaf(alpha, dphi1, beta * corr);
        acc = fmaf(val * val, wgt, acc);
    }

    #pragma unroll
    for (int off = 32; off; off >>= 1) acc += __shfl_down(acc, off);
    const int lane = tid & 63, wid = tid >> 6;
    if (lane == 0) s_red[wid] = acc;
    __syncthreads();
    if (tid == 0) {
        float bs = s_red[0] + s_red[1] + s_red[2] + s_red[3];
        atomicAdd(out, bs * (1.0f / (float)NS));
    }
}

extern "C" void kernel_launch(void* const* d_in, const int* in_sizes, int n_in,
                              void* d_out, int out_size, void* d_ws, size_t ws_size,
                              hipStream_t stream) {
    const float* u_y1  = (const float*)d_in[0];
    const float* u_ym1 = (const float*)d_in[1];
    const float* u_x1  = (const float*)d_in[2];
    const float* u_xm1 = (const float*)d_in[3];
    const float* sW1 = (const float*)d_in[4];
    const float* sb1 = (const float*)d_in[5];
    const float* sW2 = (const float*)d_in[6];
    const float* sb2 = (const float*)d_in[7];
    const float* jW1 = (const float*)d_in[8];
    const float* jb1 = (const float*)d_in[9];
    const float* jW2 = (const float*)d_in[10];
    const float* jb2 = (const float*)d_in[11];
    float* out = (float*)d_out;

    if (ws_size >= WS_NEED) {
        float* tab = (float*)d_ws;                               // 4*TABSTRIDE floats
        float* partials = (float*)((char*)d_ws + TAB_BYTES);     // MGRID=512 floats
        build_tab<<<BGRID, THREADS, 0, stream>>>(
            sW1, sb1, sW2, sb2, jW1, jb1, jW2, jb2, tab);
        eval_main<<<MGRID, THREADS, 0, stream>>>(
            u_y1, u_ym1, u_x1, u_xm1, tab, partials);
        jump_loss_stage2<<<1, 256, 0, stream>>>(partials, out);
    } else {
        hipMemsetAsync(d_out, 0, sizeof(float), stream);
        direct_stage1<<<FGRID, THREADS, 0, stream>>>(
            u_y1, u_ym1, u_x1, u_xm1, sW1, sb1, sW2, sb2, jW1, jb1, jW2, jb2,
            out);
    }
}